// Round 1
// baseline (696.964 us; speedup 1.0000x reference)
//
#include <hip/hip_runtime.h>

#define NB 2
#define NSEQ 2048
#define CDIM 768
#define NH 12
#define HD 64
#define QKV_COLS 2304  // 3*CDIM

// ---------------------------------------------------------------------------
// Kernel 1: qkv = x[4096,768] @ w_qkv[768,2304], epilogue splits/stores
// q,k,v as [B, H, N, 64] (head-major) for the attention kernel.
// 64x64 tile / block, 256 threads, 4x4 micro-tile per thread, K-step 16.
// ---------------------------------------------------------------------------
__global__ __launch_bounds__(256) void qkv_gemm_kernel(
    const float* __restrict__ x, const float* __restrict__ w,
    float* __restrict__ qb, float* __restrict__ kb, float* __restrict__ vb)
{
    __shared__ __align__(16) float As[16][68];  // As[k][row] (transposed A tile)
    __shared__ __align__(16) float Bs[16][68];  // Bs[k][col]
    const int t  = threadIdx.x;
    const int tx = t & 15, ty = t >> 4;
    const int m0 = blockIdx.y * 64;
    const int c0 = blockIdx.x * 64;
    const int arow = t >> 2,  acol = (t & 3) << 2;   // A: 64 rows x 16 k
    const int brow = t >> 4,  bcol = (t & 15) << 2;  // B: 16 k x 64 cols
    float acc[4][4] = {};

    for (int k0 = 0; k0 < CDIM; k0 += 16) {
        float4 av = *(const float4*)(x + (size_t)(m0 + arow) * CDIM + k0 + acol);
        float4 bv = *(const float4*)(w + (size_t)(k0 + brow) * QKV_COLS + c0 + bcol);
        __syncthreads();
        As[acol + 0][arow] = av.x;
        As[acol + 1][arow] = av.y;
        As[acol + 2][arow] = av.z;
        As[acol + 3][arow] = av.w;
        *(float4*)&Bs[brow][bcol] = bv;
        __syncthreads();
        #pragma unroll
        for (int kk = 0; kk < 16; ++kk) {
            float4 a = *(const float4*)&As[kk][ty << 2];
            float4 b = *(const float4*)&Bs[kk][tx << 2];
            float ar[4] = {a.x, a.y, a.z, a.w};
            float br[4] = {b.x, b.y, b.z, b.w};
            #pragma unroll
            for (int i = 0; i < 4; ++i)
                #pragma unroll
                for (int j = 0; j < 4; ++j)
                    acc[i][j] = fmaf(ar[i], br[j], acc[i][j]);
        }
    }

    // tile cols c0..c0+63 = exactly one (s, h) pair since 64 == HD
    const int s = c0 / CDIM;
    const int h = (c0 % CDIM) / HD;
    float* dst = (s == 0) ? qb : (s == 1) ? kb : vb;
    #pragma unroll
    for (int i = 0; i < 4; ++i) {
        int row = m0 + (ty << 2) + i;
        int b = row >> 11;            // /NSEQ
        int n = row & (NSEQ - 1);
        float4 o = {acc[i][0], acc[i][1], acc[i][2], acc[i][3]};
        *(float4*)(dst + (((size_t)(b * NH + h) * NSEQ + n) << 6) + (tx << 2)) = o;
    }
}

// ---------------------------------------------------------------------------
// Kernel 2: flash-style masked attention, one block per (q-tile of 64, h, b).
// Faithful to reference: e = exp(logit)*mask (no max subtraction), then /sum.
// S-tile and PV both 64x64 with 4x4 micro-tiles; Q/K/P transposed in LDS so
// inner loops are conflict-free b128 reads.
// ---------------------------------------------------------------------------
__global__ __launch_bounds__(256) void attn_kernel(
    const float* __restrict__ qb, const float* __restrict__ kb,
    const float* __restrict__ vb, const int* __restrict__ mask,
    float* __restrict__ ao)
{
    __shared__ __align__(16) float QsT[64][68];  // [d][q]
    __shared__ __align__(16) float KsT[64][68];  // [d][k]
    __shared__ __align__(16) float Vs[64][68];   // [k][d]
    __shared__ __align__(16) float PsT[64][68];  // [k][q]
    __shared__ float lpart[16][68];
    __shared__ float lacc[64];
    __shared__ float ms[64];

    const int t  = threadIdx.x;
    const int tx = t & 15, ty = t >> 4;
    const int qy = ty << 2, dx = tx << 2;  // dx doubles as k-col in S phase
    const int q0 = blockIdx.x * 64;
    const int h  = blockIdx.y, b = blockIdx.z;
    const size_t head_off = ((size_t)(b * NH + h) * NSEQ) << 6;
    const float* qp = qb + head_off;
    const float* kp = kb + head_off;
    const float* vp = vb + head_off;
    const int lrow = t >> 2, lcol = (t & 3) << 2;

    #pragma unroll
    for (int jj = 0; jj < 4; ++jj) {
        int d = lcol + (jj << 4);
        float4 v4 = *(const float4*)(qp + ((size_t)(q0 + lrow) << 6) + d);
        QsT[d + 0][lrow] = v4.x;
        QsT[d + 1][lrow] = v4.y;
        QsT[d + 2][lrow] = v4.z;
        QsT[d + 3][lrow] = v4.w;
    }
    if (t < 64) lacc[t] = 0.0f;
    float oacc[4][4] = {};

    for (int kt = 0; kt < NSEQ; kt += 64) {
        __syncthreads();  // prev-iter PV done; safe to restage K/V/mask
        #pragma unroll
        for (int jj = 0; jj < 4; ++jj) {
            int d = lcol + (jj << 4);
            float4 kv = *(const float4*)(kp + ((size_t)(kt + lrow) << 6) + d);
            KsT[d + 0][lrow] = kv.x;
            KsT[d + 1][lrow] = kv.y;
            KsT[d + 2][lrow] = kv.z;
            KsT[d + 3][lrow] = kv.w;
            float4 vv = *(const float4*)(vp + ((size_t)(kt + lrow) << 6) + d);
            *(float4*)&Vs[lrow][d] = vv;
        }
        if (t < 64) ms[t] = (float)mask[b * NSEQ + kt + t];
        __syncthreads();

        // S = Q @ K^T  (inner dim d = 64)
        float s[4][4] = {};
        #pragma unroll 8
        for (int dd = 0; dd < 64; ++dd) {
            float4 a = *(const float4*)&QsT[dd][qy];
            float4 kk4 = *(const float4*)&KsT[dd][dx];
            float ar[4] = {a.x, a.y, a.z, a.w};
            float kr[4] = {kk4.x, kk4.y, kk4.z, kk4.w};
            #pragma unroll
            for (int i = 0; i < 4; ++i)
                #pragma unroll
                for (int j = 0; j < 4; ++j)
                    s[i][j] = fmaf(ar[i], kr[j], s[i][j]);
        }

        // e = exp(s * scale) * mask; write P^T + row-sum partials
        float rs[4] = {0.f, 0.f, 0.f, 0.f};
        #pragma unroll
        for (int j = 0; j < 4; ++j) {
            float mj = ms[dx + j];
            float4 col;
            col.x = __expf(s[0][j] * 0.125f) * mj;
            col.y = __expf(s[1][j] * 0.125f) * mj;
            col.z = __expf(s[2][j] * 0.125f) * mj;
            col.w = __expf(s[3][j] * 0.125f) * mj;
            *(float4*)&PsT[dx + j][qy] = col;
            rs[0] += col.x; rs[1] += col.y; rs[2] += col.z; rs[3] += col.w;
        }
        #pragma unroll
        for (int i = 0; i < 4; ++i) lpart[tx][qy + i] = rs[i];
        __syncthreads();

        if (t < 64) {
            float ssum = 0.0f;
            #pragma unroll
            for (int xx = 0; xx < 16; ++xx) ssum += lpart[xx][t];
            lacc[t] += ssum;
        }

        // O += P @ V  (inner dim k = 64)
        #pragma unroll 8
        for (int kk = 0; kk < 64; ++kk) {
            float4 p = *(const float4*)&PsT[kk][qy];
            float4 vv = *(const float4*)&Vs[kk][dx];
            float pr[4] = {p.x, p.y, p.z, p.w};
            float vr[4] = {vv.x, vv.y, vv.z, vv.w};
            #pragma unroll
            for (int i = 0; i < 4; ++i)
                #pragma unroll
                for (int j = 0; j < 4; ++j)
                    oacc[i][j] = fmaf(pr[i], vr[j], oacc[i][j]);
        }
    }
    __syncthreads();

    #pragma unroll
    for (int i = 0; i < 4; ++i) {
        float inv = 1.0f / lacc[qy + i];
        int n = q0 + qy + i;
        float4 o = {oacc[i][0] * inv, oacc[i][1] * inv,
                    oacc[i][2] * inv, oacc[i][3] * inv};
        *(float4*)(ao + (size_t)(b * NSEQ + n) * CDIM + h * HD + dx) = o;
    }
}

// ---------------------------------------------------------------------------
// Kernel 3: out = ao[4096,768] @ w_proj[768,768] + b_proj
// ---------------------------------------------------------------------------
__global__ __launch_bounds__(256) void proj_gemm_kernel(
    const float* __restrict__ a, const float* __restrict__ w,
    const float* __restrict__ bias, float* __restrict__ out)
{
    __shared__ __align__(16) float As[16][68];
    __shared__ __align__(16) float Bs[16][68];
    const int t  = threadIdx.x;
    const int tx = t & 15, ty = t >> 4;
    const int m0 = blockIdx.y * 64;
    const int c0 = blockIdx.x * 64;
    const int arow = t >> 2,  acol = (t & 3) << 2;
    const int brow = t >> 4,  bcol = (t & 15) << 2;
    float acc[4][4] = {};

    for (int k0 = 0; k0 < CDIM; k0 += 16) {
        float4 av = *(const float4*)(a + (size_t)(m0 + arow) * CDIM + k0 + acol);
        float4 bv = *(const float4*)(w + (size_t)(k0 + brow) * CDIM + c0 + bcol);
        __syncthreads();
        As[acol + 0][arow] = av.x;
        As[acol + 1][arow] = av.y;
        As[acol + 2][arow] = av.z;
        As[acol + 3][arow] = av.w;
        *(float4*)&Bs[brow][bcol] = bv;
        __syncthreads();
        #pragma unroll
        for (int kk = 0; kk < 16; ++kk) {
            float4 av2 = *(const float4*)&As[kk][ty << 2];
            float4 bv2 = *(const float4*)&Bs[kk][tx << 2];
            float ar[4] = {av2.x, av2.y, av2.z, av2.w};
            float br[4] = {bv2.x, bv2.y, bv2.z, bv2.w};
            #pragma unroll
            for (int i = 0; i < 4; ++i)
                #pragma unroll
                for (int j = 0; j < 4; ++j)
                    acc[i][j] = fmaf(ar[i], br[j], acc[i][j]);
        }
    }

    float4 bias4 = *(const float4*)(bias + c0 + (tx << 2));
    #pragma unroll
    for (int i = 0; i < 4; ++i) {
        int row = m0 + (ty << 2) + i;
        float4 o = {acc[i][0] + bias4.x, acc[i][1] + bias4.y,
                    acc[i][2] + bias4.z, acc[i][3] + bias4.w};
        *(float4*)(out + (size_t)row * CDIM + c0 + (tx << 2)) = o;
    }
}

extern "C" void kernel_launch(void* const* d_in, const int* in_sizes, int n_in,
                              void* d_out, int out_size, void* d_ws, size_t ws_size,
                              hipStream_t stream)
{
    const float* x      = (const float*)d_in[0];
    const int*   mask   = (const int*)d_in[1];
    const float* w_qkv  = (const float*)d_in[2];
    const float* w_proj = (const float*)d_in[3];
    const float* b_proj = (const float*)d_in[4];
    float* out = (float*)d_out;

    const size_t per_head_buf = (size_t)NB * NH * NSEQ * HD;  // 3,145,728 floats
    float* qb = (float*)d_ws;
    float* kb = qb + per_head_buf;
    float* vb = kb + per_head_buf;
    float* ao = vb + per_head_buf;   // [4096, 768] attention output

    dim3 blk(256);
    qkv_gemm_kernel<<<dim3(QKV_COLS / 64, (NB * NSEQ) / 64), blk, 0, stream>>>(
        x, w_qkv, qb, kb, vb);
    attn_kernel<<<dim3(NSEQ / 64, NH, NB), blk, 0, stream>>>(
        qb, kb, vb, mask, ao);
    proj_gemm_kernel<<<dim3(CDIM / 64, (NB * NSEQ) / 64), blk, 0, stream>>>(
        ao, w_proj, b_proj, out);
}

// Round 2
// 213.715 us; speedup vs baseline: 3.2612x; 3.2612x over previous
//
#include <hip/hip_runtime.h>
#include <cstdint>

#define NB 2
#define NSEQ 2048
#define CDIM 768
#define NH 12
#define HD 64
#define NTOK (NB*NSEQ)        // 4096
#define QKV_COLS (3*CDIM)     // 2304

typedef short bf16x8 __attribute__((ext_vector_type(8)));   // 8 bf16 = 4 VGPR
typedef float f32x4  __attribute__((ext_vector_type(4)));
typedef short short4v __attribute__((ext_vector_type(4)));  // 8B packed store

#define MFMA16(a,b,c) __builtin_amdgcn_mfma_f32_16x16x32_bf16(a,b,c,0,0,0)

// fp32 -> bf16 round-to-nearest-even (values finite; no NaN care needed)
__device__ __forceinline__ short f2b(float f) {
    uint32_t u = __builtin_bit_cast(uint32_t, f);
    u += 0x7fffu + ((u >> 16) & 1u);
    return (short)(u >> 16);
}

// ---------------------------------------------------------------------------
// Elementwise fp32 -> bf16 (x)
// ---------------------------------------------------------------------------
__global__ __launch_bounds__(256) void convert_f32_bf16(
    const float* __restrict__ in, short* __restrict__ out, int n4)
{
    int i = blockIdx.x * 256 + threadIdx.x;
    if (i < n4) {
        float4 v = ((const float4*)in)[i];
        short4v o = { f2b(v.x), f2b(v.y), f2b(v.z), f2b(v.w) };
        ((short4v*)out)[i] = o;
    }
}

// ---------------------------------------------------------------------------
// w[K][NC] fp32 -> wt[NC][K] bf16 (transpose so B-frags read contiguous K)
// ---------------------------------------------------------------------------
__global__ __launch_bounds__(256) void transpose_f32_bf16(
    const float* __restrict__ w, short* __restrict__ wt, int K, int NC)
{
    __shared__ float tile[32][33];
    const int n0 = blockIdx.x * 32, k0 = blockIdx.y * 32;
    const int t = threadIdx.x;
    #pragma unroll
    for (int i = 0; i < 4; ++i) {
        int idx = t + i * 256; int r = idx >> 5, c = idx & 31;
        tile[r][c] = w[(size_t)(k0 + r) * NC + n0 + c];
    }
    __syncthreads();
    #pragma unroll
    for (int i = 0; i < 4; ++i) {
        int idx = t + i * 256; int r = idx >> 5, c = idx & 31;
        wt[(size_t)(n0 + r) * K + k0 + c] = f2b(tile[c][r]);
    }
}

// ---------------------------------------------------------------------------
// GEMM1: qkv = xb[4096][768] @ wqt[2304][768]^T, both bf16 row-major-K.
// 128x128 block tile, 4 waves of 64x64 (4x4 tiles of 16x16x32 MFMA), BK=32.
// Epilogue: q,k -> [BH][N][64] bf16; v -> TRANSPOSED [BH][64][N] bf16.
// ---------------------------------------------------------------------------
__global__ __launch_bounds__(256) void gemm_qkv(
    const short* __restrict__ A, const short* __restrict__ Bt,
    short* __restrict__ qb, short* __restrict__ kb, short* __restrict__ vt)
{
    __shared__ short As[128][40];   // +8 pad: row stride 80B, balanced b128 reads
    __shared__ short Bs[128][40];
    const int t = threadIdx.x;
    const int lane = t & 63, wid = t >> 6;
    const int quad = lane >> 4, l16 = lane & 15;
    const int wm = wid >> 1, wn = wid & 1;
    const int m0 = blockIdx.y * 128, n0 = blockIdx.x * 128;
    const int r0 = t >> 2, o0 = (t & 3) * 8;

    f32x4 acc[4][4] = {};
    const short* ap0 = A + (size_t)(m0 + r0) * CDIM + o0;
    const short* ap1 = ap0 + (size_t)64 * CDIM;
    const short* bp0 = Bt + (size_t)(n0 + r0) * CDIM + o0;
    const short* bp1 = bp0 + (size_t)64 * CDIM;

    for (int k0 = 0; k0 < CDIM; k0 += 32) {
        float4 a0 = *(const float4*)(ap0 + k0);
        float4 a1 = *(const float4*)(ap1 + k0);
        float4 b0 = *(const float4*)(bp0 + k0);
        float4 b1 = *(const float4*)(bp1 + k0);
        __syncthreads();
        *(float4*)&As[r0][o0]      = a0;
        *(float4*)&As[r0 + 64][o0] = a1;
        *(float4*)&Bs[r0][o0]      = b0;
        *(float4*)&Bs[r0 + 64][o0] = b1;
        __syncthreads();
        bf16x8 af[4], bf[4];
        #pragma unroll
        for (int i = 0; i < 4; ++i)
            af[i] = *(const bf16x8*)&As[wm*64 + i*16 + l16][quad*8];
        #pragma unroll
        for (int j = 0; j < 4; ++j)
            bf[j] = *(const bf16x8*)&Bs[wn*64 + j*16 + l16][quad*8];
        #pragma unroll
        for (int i = 0; i < 4; ++i)
            #pragma unroll
            for (int j = 0; j < 4; ++j)
                acc[i][j] = MFMA16(af[i], bf[j], acc[i][j]);
    }

    // epilogue: C row = m0+wm*64+i*16+quad*4+r, col = n0+wn*64+j*16+l16
    const int b = m0 >> 11;                 // block never straddles batch
    const int colbase = n0 + wn * 64;       // multiple of 64 -> s,h fixed per wave
    const int s = colbase / CDIM;
    const int h = (colbase - s * CDIM) >> 6;
    #pragma unroll
    for (int i = 0; i < 4; ++i) {
        int n = (m0 + wm*64 + i*16 + quad*4) & (NSEQ - 1);
        if (s < 2) {
            short* dst = (s == 0 ? qb : kb) + ((size_t)(b*NH + h) * NSEQ + n) * HD;
            #pragma unroll
            for (int j = 0; j < 4; ++j) {
                int d = j*16 + l16;
                #pragma unroll
                for (int r = 0; r < 4; ++r)
                    dst[(size_t)r * HD + d] = f2b(acc[i][j][r]);
            }
        } else {
            short* dst = vt + ((size_t)(b*NH + h) * HD) * NSEQ + n;
            #pragma unroll
            for (int j = 0; j < 4; ++j) {
                int d = j*16 + l16;
                short4v o = { f2b(acc[i][j][0]), f2b(acc[i][j][1]),
                              f2b(acc[i][j][2]), f2b(acc[i][j][3]) };
                *(short4v*)(dst + (size_t)d * NSEQ) = o;   // 4 consecutive tokens
            }
        }
    }
}

// ---------------------------------------------------------------------------
// Flash attention, MFMA. Block = (64 q) x head x batch. K/V tiles of 64 keys.
// S: A=Q[q][d], B=K^T via Ks[key][d] rows. P: exp(s*scale)*mask, bf16 to LDS
// (wave-private rows -> no barrier before PV). PV: A=P[q][key], B=V via
// Vs[d][key] rows (v stored transposed by GEMM1). Row-sums via 16-lane
// butterfly; lanes end up holding exactly the rows they normalize.
// ---------------------------------------------------------------------------
__global__ __launch_bounds__(256) void attn_kernel(
    const short* __restrict__ qb, const short* __restrict__ kb,
    const short* __restrict__ vt, const int* __restrict__ mask,
    short* __restrict__ ao)
{
    __shared__ short Qs[64][72], Ks[64][72], Vs[64][72], Ps[64][72];
    __shared__ float ms[64];
    const int t = threadIdx.x;
    const int lane = t & 63, wid = t >> 6;
    const int quad = lane >> 4, l16 = lane & 15;
    const int q0 = blockIdx.x * 64, h = blockIdx.y, b = blockIdx.z;
    const size_t hoff = (size_t)(b*NH + h) * NSEQ * HD;
    const short* qp = qb + hoff;
    const short* kp = kb + hoff;
    const short* vp = vt + hoff;            // [HD][NSEQ]
    const int sr = t >> 3, so = (t & 7) * 8;

    *(float4*)&Qs[sr][so]      = *(const float4*)(qp + (size_t)(q0 + sr) * HD + so);
    *(float4*)&Qs[sr + 32][so] = *(const float4*)(qp + (size_t)(q0 + sr + 32) * HD + so);

    f32x4 o_acc[4] = {};
    float l[4] = {0.f, 0.f, 0.f, 0.f};

    for (int kt = 0; kt < NSEQ; kt += 64) {
        __syncthreads();   // prev iter's PV reads of Ks/Vs done
        *(float4*)&Ks[sr][so]      = *(const float4*)(kp + (size_t)(kt + sr) * HD + so);
        *(float4*)&Ks[sr + 32][so] = *(const float4*)(kp + (size_t)(kt + sr + 32) * HD + so);
        *(float4*)&Vs[sr][so]      = *(const float4*)(vp + (size_t)sr * NSEQ + kt + so);
        *(float4*)&Vs[sr + 32][so] = *(const float4*)(vp + (size_t)(sr + 32) * NSEQ + kt + so);
        if (t < 64) ms[t] = (float)mask[b * NSEQ + kt + t];
        __syncthreads();

        // S = Q K^T over d=64 (2 MFMA k-steps)
        bf16x8 qf0 = *(const bf16x8*)&Qs[wid*16 + l16][quad*8];
        bf16x8 qf1 = *(const bf16x8*)&Qs[wid*16 + l16][32 + quad*8];
        f32x4 s[4] = {};
        #pragma unroll
        for (int j = 0; j < 4; ++j) {
            bf16x8 kf0 = *(const bf16x8*)&Ks[j*16 + l16][quad*8];
            bf16x8 kf1 = *(const bf16x8*)&Ks[j*16 + l16][32 + quad*8];
            s[j] = MFMA16(qf0, kf0, s[j]);
            s[j] = MFMA16(qf1, kf1, s[j]);
        }

        // P = exp(s/8)*mask  (faithful: no max subtraction), bf16 to LDS
        float part[4] = {0.f, 0.f, 0.f, 0.f};
        #pragma unroll
        for (int j = 0; j < 4; ++j) {
            float mj = ms[j*16 + l16];
            #pragma unroll
            for (int r = 0; r < 4; ++r) {
                float e = __expf(s[j][r] * 0.125f) * mj;
                part[r] += e;
                Ps[wid*16 + quad*4 + r][j*16 + l16] = f2b(e);
            }
        }
        #pragma unroll
        for (int r = 0; r < 4; ++r) {
            float p = part[r];
            p += __shfl_xor(p, 1, 16);
            p += __shfl_xor(p, 2, 16);
            p += __shfl_xor(p, 4, 16);
            p += __shfl_xor(p, 8, 16);
            l[r] += p;   // rowsum for q = wid*16 + quad*4 + r
        }

        // O += P V  (P rows wave-private: compiler's lgkmcnt wait suffices)
        bf16x8 pf0 = *(const bf16x8*)&Ps[wid*16 + l16][quad*8];
        bf16x8 pf1 = *(const bf16x8*)&Ps[wid*16 + l16][32 + quad*8];
        #pragma unroll
        for (int j = 0; j < 4; ++j) {
            bf16x8 vf0 = *(const bf16x8*)&Vs[j*16 + l16][quad*8];
            bf16x8 vf1 = *(const bf16x8*)&Vs[j*16 + l16][32 + quad*8];
            o_acc[j] = MFMA16(pf0, vf0, o_acc[j]);
            o_acc[j] = MFMA16(pf1, vf1, o_acc[j]);
        }
    }

    // epilogue: C rows quad*4+r match the l[r] this lane holds
    float inv[4];
    #pragma unroll
    for (int r = 0; r < 4; ++r) inv[r] = 1.0f / l[r];
    const int tok = b * NSEQ + q0 + wid*16 + quad*4;
    #pragma unroll
    for (int j = 0; j < 4; ++j) {
        int d = h * HD + j*16 + l16;
        #pragma unroll
        for (int r = 0; r < 4; ++r)
            ao[(size_t)(tok + r) * CDIM + d] = f2b(o_acc[j][r] * inv[r]);
    }
}

// ---------------------------------------------------------------------------
// GEMM2: out = ao[4096][768] @ wpt[768][768]^T + bias, fp32 out.
// ---------------------------------------------------------------------------
__global__ __launch_bounds__(256) void gemm_proj(
    const short* __restrict__ A, const short* __restrict__ Bt,
    const float* __restrict__ bias, float* __restrict__ out)
{
    __shared__ short As[128][40];
    __shared__ short Bs[128][40];
    const int t = threadIdx.x;
    const int lane = t & 63, wid = t >> 6;
    const int quad = lane >> 4, l16 = lane & 15;
    const int wm = wid >> 1, wn = wid & 1;
    const int m0 = blockIdx.y * 128, n0 = blockIdx.x * 128;
    const int r0 = t >> 2, o0 = (t & 3) * 8;

    f32x4 acc[4][4] = {};
    const short* ap0 = A + (size_t)(m0 + r0) * CDIM + o0;
    const short* ap1 = ap0 + (size_t)64 * CDIM;
    const short* bp0 = Bt + (size_t)(n0 + r0) * CDIM + o0;
    const short* bp1 = bp0 + (size_t)64 * CDIM;

    for (int k0 = 0; k0 < CDIM; k0 += 32) {
        float4 a0 = *(const float4*)(ap0 + k0);
        float4 a1 = *(const float4*)(ap1 + k0);
        float4 b0 = *(const float4*)(bp0 + k0);
        float4 b1 = *(const float4*)(bp1 + k0);
        __syncthreads();
        *(float4*)&As[r0][o0]      = a0;
        *(float4*)&As[r0 + 64][o0] = a1;
        *(float4*)&Bs[r0][o0]      = b0;
        *(float4*)&Bs[r0 + 64][o0] = b1;
        __syncthreads();
        bf16x8 af[4], bf[4];
        #pragma unroll
        for (int i = 0; i < 4; ++i)
            af[i] = *(const bf16x8*)&As[wm*64 + i*16 + l16][quad*8];
        #pragma unroll
        for (int j = 0; j < 4; ++j)
            bf[j] = *(const bf16x8*)&Bs[wn*64 + j*16 + l16][quad*8];
        #pragma unroll
        for (int i = 0; i < 4; ++i)
            #pragma unroll
            for (int j = 0; j < 4; ++j)
                acc[i][j] = MFMA16(af[i], bf[j], acc[i][j]);
    }

    #pragma unroll
    for (int i = 0; i < 4; ++i) {
        int mrow = m0 + wm*64 + i*16 + quad*4;
        #pragma unroll
        for (int j = 0; j < 4; ++j) {
            int col = n0 + wn*64 + j*16 + l16;
            float bv = bias[col];
            #pragma unroll
            for (int r = 0; r < 4; ++r)
                out[(size_t)(mrow + r) * CDIM + col] = acc[i][j][r] + bv;
        }
    }
}

extern "C" void kernel_launch(void* const* d_in, const int* in_sizes, int n_in,
                              void* d_out, int out_size, void* d_ws, size_t ws_size,
                              hipStream_t stream)
{
    const float* x      = (const float*)d_in[0];
    const int*   mask   = (const int*)d_in[1];
    const float* w_qkv  = (const float*)d_in[2];
    const float* w_proj = (const float*)d_in[3];
    const float* b_proj = (const float*)d_in[4];
    float* out = (float*)d_out;

    const size_t SZ = (size_t)NTOK * CDIM;       // 3,145,728
    short* xb  = (short*)d_ws;                   // [4096][768]
    short* wqt = xb  + SZ;                       // [2304][768]
    short* wpt = wqt + (size_t)QKV_COLS * CDIM;  // [768][768]
    short* qb  = wpt + (size_t)CDIM * CDIM;      // [BH][N][64]
    short* kb  = qb  + SZ;                       // [BH][N][64]
    short* vt  = kb  + SZ;                       // [BH][64][N]  (transposed!)
    short* ao  = vt  + SZ;                       // [4096][768]

    dim3 blk(256);
    convert_f32_bf16<<<(SZ/4 + 255)/256, blk, 0, stream>>>(x, xb, (int)(SZ/4));
    transpose_f32_bf16<<<dim3(QKV_COLS/32, CDIM/32), blk, 0, stream>>>(w_qkv, wqt, CDIM, QKV_COLS);
    transpose_f32_bf16<<<dim3(CDIM/32, CDIM/32),     blk, 0, stream>>>(w_proj, wpt, CDIM, CDIM);
    gemm_qkv<<<dim3(QKV_COLS/128, NTOK/128), blk, 0, stream>>>(xb, wqt, qb, kb, vt);
    attn_kernel<<<dim3(NSEQ/64, NH, NB), blk, 0, stream>>>(qb, kb, vt, mask, ao);
    gemm_proj<<<dim3(CDIM/128, NTOK/128), blk, 0, stream>>>(ao, wpt, b_proj, out);
}